// Round 1
// baseline (2752.357 us; speedup 1.0000x reference)
//
#include <hip/hip_runtime.h>
#include <math.h>

// ============================================================================
// LayoutEncoder: conv1(1x1) -> cbn -> lrelu -> [4x (4x4 s2 conv -> cbn (+lrelu x2))]
//                -> 3-layer ConvLSTM (5x5, 16x16 images)
// All f32 this round (threshold is 2% of max|ref| -> huge headroom).
// ============================================================================

#define LEAK 0.2f

// ---------------- conv1: 1x1 conv 512->32, pad=1 (border stays 0 from memset) ----
// grid (64 row-groups, 8 n), 256 threads. Each thread: 4 rows x 32 outch.
__global__ __launch_bounds__(256) void conv1_kernel(
    const float* __restrict__ h, const float* __restrict__ w, float* __restrict__ out)
{
  __shared__ float wt[256 * 32];   // wt[c_local*32 + o], half of W at a time (32KB)
  const int n  = blockIdx.y;
  const int r0 = blockIdx.x * 4;
  const int ix = threadIdx.x;
  const bool lanev = (ix < 254);
  const bool rv2 = (r0 + 2) < 254, rv3 = (r0 + 3) < 254;

  float acc[4][32];
#pragma unroll
  for (int r = 0; r < 4; ++r)
#pragma unroll
    for (int o = 0; o < 32; ++o) acc[r][o] = 0.f;

  const float* hp = h + (size_t)n * 512 * 64516 + (size_t)r0 * 254 + ix;

  for (int half = 0; half < 2; ++half) {
    const int cbase = half * 256;
    for (int i = threadIdx.x; i < 256 * 32; i += 256) {
      int c = i >> 5, o = i & 31;
      wt[i] = w[(size_t)o * 512 + cbase + c];
    }
    __syncthreads();
    if (lanev) {
#pragma unroll 4
      for (int c = 0; c < 256; ++c) {
        const float* pc = hp + (size_t)(cbase + c) * 64516;
        float vr[4];
        vr[0] = pc[0];
        vr[1] = pc[254];
        vr[2] = rv2 ? pc[2 * 254] : 0.f;
        vr[3] = rv3 ? pc[3 * 254] : 0.f;
        const float4* wp = (const float4*)&wt[c * 32];
#pragma unroll
        for (int q = 0; q < 8; ++q) {
          float4 w4 = wp[q];
#pragma unroll
          for (int r = 0; r < 4; ++r) {
            acc[r][4 * q + 0] = fmaf(vr[r], w4.x, acc[r][4 * q + 0]);
            acc[r][4 * q + 1] = fmaf(vr[r], w4.y, acc[r][4 * q + 1]);
            acc[r][4 * q + 2] = fmaf(vr[r], w4.z, acc[r][4 * q + 2]);
            acc[r][4 * q + 3] = fmaf(vr[r], w4.w, acc[r][4 * q + 3]);
          }
        }
      }
    }
    __syncthreads();
  }

  if (lanev) {
    float* op = out + (size_t)n * 32 * 65536 + (size_t)(r0 + 1) * 256 + (ix + 1);
#pragma unroll
    for (int o = 0; o < 32; ++o) {
      float* oc = op + (size_t)o * 65536;
      oc[0]   = acc[0][o];
      oc[256] = acc[1][o];
      if (rv2) oc[512] = acc[2][o];
      if (rv3) oc[768] = acc[3][o];
    }
  }
}

// ---------------- generic 4x4 stride-2 pad-1 conv ---------------------------
// 256 threads = 16x16 output tile. OCH out-channels per block, CCH in-ch chunk.
// grid: (tiles, O/OCH, N*CSPLIT). CSPLIT>1 -> atomicAdd into pre-zeroed out.
template <int C, int O, int HIN, int HOUT, int OCH, int CCH, int CSPLIT>
__global__ __launch_bounds__(256) void conv4x4_kernel(
    const float* __restrict__ in, const float* __restrict__ w, float* __restrict__ out)
{
  constexpr int TW = HOUT / 16;
  __shared__ float tile_in[CCH][34 * 34];
  __shared__ float swt[CCH][16][OCH];

  const int tile = blockIdx.x, ty = tile / TW, tx = tile % TW;
  const int o0 = blockIdx.y * OCH;
  const int n = blockIdx.z / CSPLIT, cs = blockIdx.z % CSPLIT;
  const int px = threadIdx.x & 15, py = threadIdx.x >> 4;
  const int iy0 = ty * 32 - 1, ix0 = tx * 32 - 1;

  float acc[OCH];
#pragma unroll
  for (int i = 0; i < OCH; ++i) acc[i] = 0.f;

  constexpr int CPER = C / CSPLIT;
  const int cbeg = cs * CPER;

  for (int c0 = cbeg; c0 < cbeg + CPER; c0 += CCH) {
    for (int idx = threadIdx.x; idx < CCH * 34 * 34; idx += 256) {
      int cc = idx / (34 * 34);
      int r = idx - cc * (34 * 34);
      int yy = r / 34, xx = r - yy * 34;
      int iy = iy0 + yy, ix = ix0 + xx;
      float v = 0.f;
      if ((unsigned)iy < (unsigned)HIN && (unsigned)ix < (unsigned)HIN)
        v = in[(((size_t)n * C + (c0 + cc)) * HIN + iy) * HIN + ix];
      tile_in[cc][r] = v;
    }
    for (int idx = threadIdx.x; idx < CCH * 16 * OCH; idx += 256) {
      int cc = idx / (16 * OCH);
      int r = idx - cc * (16 * OCH);
      int k = r / OCH, oo = r - k * OCH;
      swt[cc][k][oo] = w[(((size_t)(o0 + oo) * C + (c0 + cc)) * 16) + k];
    }
    __syncthreads();

    const int ibase = (py * 2) * 34 + px * 2;
    for (int cc = 0; cc < CCH; ++cc) {
      const float* tin = &tile_in[cc][ibase];
#pragma unroll
      for (int ky = 0; ky < 4; ++ky)
#pragma unroll
        for (int kx = 0; kx < 4; ++kx) {
          float v = tin[ky * 34 + kx];
          const float4* wp = (const float4*)&swt[cc][ky * 4 + kx][0];
#pragma unroll
          for (int q = 0; q < OCH / 4; ++q) {
            float4 w4 = wp[q];
            acc[4 * q + 0] = fmaf(v, w4.x, acc[4 * q + 0]);
            acc[4 * q + 1] = fmaf(v, w4.y, acc[4 * q + 1]);
            acc[4 * q + 2] = fmaf(v, w4.z, acc[4 * q + 2]);
            acc[4 * q + 3] = fmaf(v, w4.w, acc[4 * q + 3]);
          }
        }
    }
    __syncthreads();
  }

  const int oy = ty * 16 + py, ox = tx * 16 + px;
  float* op = out + (((size_t)n * O + o0) * HOUT + oy) * HOUT + ox;
#pragma unroll
  for (int oo = 0; oo < OCH; ++oo) {
    if (CSPLIT > 1) atomicAdd(op + (size_t)oo * HOUT * HOUT, acc[oo]);
    else            op[(size_t)oo * HOUT * HOUT] = acc[oo];
  }
}

// ---------------- 5x5 stride-1 pad-2 conv on 16x16, concat(x, h) input ------
// 256 threads = whole 16x16 image. grid: (O/OCH, B, CSPLIT). AtomicAdd out.
template <int CX, int HH, int OCH, int CCH, int CSPLIT>
__global__ __launch_bounds__(256) void conv5x5_kernel(
    const float* __restrict__ xin, int xbstride,
    const float* __restrict__ hin,
    const float* __restrict__ w, float* __restrict__ out)
{
  constexpr int C = CX + HH;
  constexpr int O = 4 * HH;
  __shared__ float tile_in[CCH][20 * 20];
  __shared__ float swt[CCH][25][OCH];

  const int o0 = blockIdx.x * OCH;
  const int b = blockIdx.y, cs = blockIdx.z;
  const int px = threadIdx.x & 15, py = threadIdx.x >> 4;

  float acc[OCH];
#pragma unroll
  for (int i = 0; i < OCH; ++i) acc[i] = 0.f;

  constexpr int CPER = C / CSPLIT;
  const int cbeg = cs * CPER;

  for (int c0 = cbeg; c0 < cbeg + CPER; c0 += CCH) {
    for (int idx = threadIdx.x; idx < CCH * 400; idx += 256) {
      int cc = idx / 400;
      int r = idx - cc * 400;
      int yy = r / 20, xx = r - yy * 20;
      int iy = yy - 2, ix = xx - 2;
      int c = c0 + cc;
      float v = 0.f;
      if ((unsigned)iy < 16u && (unsigned)ix < 16u) {
        if (c < CX) v = xin[(size_t)b * xbstride + ((size_t)c << 8) + (iy << 4) + ix];
        else        v = hin[(((size_t)b * HH + (c - CX)) << 8) + (iy << 4) + ix];
      }
      tile_in[cc][r] = v;
    }
    for (int idx = threadIdx.x; idx < CCH * 25 * OCH; idx += 256) {
      int cc = idx / (25 * OCH);
      int r = idx - cc * (25 * OCH);
      int k = r / OCH, oo = r - k * OCH;
      swt[cc][k][oo] = w[((size_t)(o0 + oo) * C + (c0 + cc)) * 25 + k];
    }
    __syncthreads();

    const int ibase = py * 20 + px;
    for (int cc = 0; cc < CCH; ++cc) {
      const float* tin = &tile_in[cc][ibase];
#pragma unroll
      for (int ky = 0; ky < 5; ++ky)
#pragma unroll
        for (int kx = 0; kx < 5; ++kx) {
          float v = tin[ky * 20 + kx];
          const float4* wp = (const float4*)&swt[cc][ky * 5 + kx][0];
#pragma unroll
          for (int q = 0; q < OCH / 4; ++q) {
            float4 w4 = wp[q];
            acc[4 * q + 0] = fmaf(v, w4.x, acc[4 * q + 0]);
            acc[4 * q + 1] = fmaf(v, w4.y, acc[4 * q + 1]);
            acc[4 * q + 2] = fmaf(v, w4.z, acc[4 * q + 2]);
            acc[4 * q + 3] = fmaf(v, w4.w, acc[4 * q + 3]);
          }
        }
    }
    __syncthreads();
  }

  float* op = out + (((size_t)b * O + o0) << 8) + (py << 4) + px;
#pragma unroll
  for (int oo = 0; oo < OCH; ++oo) atomicAdd(op + ((size_t)oo << 8), acc[oo]);
}

// ---------------- mean/var: two-level deterministic reduction ---------------
__global__ __launch_bounds__(256) void meanvar_part_kernel(
    const float* __restrict__ x, float* __restrict__ part,
    int C, int lhw, int ntot, int S)
{
  const int c = blockIdx.x, s = blockIdx.y;
  const int len = ntot / S;
  const int hwm = (1 << lhw) - 1;
  float sum = 0.f, sq = 0.f;
  for (int j = s * len + threadIdx.x; j < (s + 1) * len; j += 256) {
    int n = j >> lhw, p = j & hwm;
    float v = x[(((size_t)n * C + c) << lhw) + p];
    sum += v; sq += v * v;
  }
  for (int off = 32; off; off >>= 1) {
    sum += __shfl_down(sum, off);
    sq  += __shfl_down(sq, off);
  }
  __shared__ float red[2][4];
  const int wid = threadIdx.x >> 6;
  if ((threadIdx.x & 63) == 0) { red[0][wid] = sum; red[1][wid] = sq; }
  __syncthreads();
  if (threadIdx.x == 0) {
    sum = red[0][0] + red[0][1] + red[0][2] + red[0][3];
    sq  = red[1][0] + red[1][1] + red[1][2] + red[1][3];
    part[((size_t)c * S + s) * 2]     = sum;
    part[((size_t)c * S + s) * 2 + 1] = sq;
  }
}

__global__ __launch_bounds__(64) void meanvar_fin_kernel(
    const float* __restrict__ part, float* __restrict__ stats, int C, int S, float invN)
{
  int c = blockIdx.x * 64 + threadIdx.x;
  if (c >= C) return;
  float sum = 0.f, sq = 0.f;
  for (int s = 0; s < S; ++s) {
    sum += part[((size_t)c * S + s) * 2];
    sq  += part[((size_t)c * S + s) * 2 + 1];
  }
  float mean = sum * invN;
  float var = sq * invN - mean * mean;
  stats[c] = mean;
  stats[C + c] = rsqrtf(var + 1e-5f);
}

// ---------------- conditional batchnorm apply (+ optional leaky relu) -------
template <bool LRELU>
__global__ __launch_bounds__(256) void cbn_kernel(
    float* __restrict__ x, const float* __restrict__ stats,
    const float* __restrict__ embed, const int* __restrict__ objs, int C, int lhw)
{
  const int c = blockIdx.y, n = blockIdx.z;
  const int p = blockIdx.x * 256 + threadIdx.x;
  const float mean = stats[c], rstd = stats[C + c];
  const int y = objs[n];
  const float gamma = embed[(size_t)y * 2 * C + c];
  const float beta  = embed[(size_t)y * 2 * C + C + c];
  const size_t i = (((size_t)n * C + c) << lhw) + p;
  float v = (x[i] - mean) * rstd * gamma + beta;
  if (LRELU) v = v >= 0.f ? v : LEAK * v;
  x[i] = v;
}

// ---------------- LSTM pointwise: gates -> (c, h) ---------------------------
__global__ __launch_bounds__(256) void lstm_point_kernel(
    const float* __restrict__ cc, const float* __restrict__ bias,
    float* __restrict__ cbuf, float* __restrict__ hbuf, float* __restrict__ hs, int lH)
{
  const int Hc = 1 << lH;
  const int i = blockIdx.x * 256 + threadIdx.x;   // over B*Hc*256, grid exact
  const int p = i & 255;
  const int ch = (i >> 8) & (Hc - 1);
  const int b = i >> (8 + lH);
  const float* ccb = cc + (((size_t)b * 4) << lH) * 256;
  const int base = (ch << 8) + p;
  float iv = ccb[base]                + bias[ch];
  float fv = ccb[(Hc << 8) + base]     + bias[Hc + ch];
  float ov = ccb[(2 * Hc << 8) + base] + bias[2 * Hc + ch];
  float gv = ccb[(3 * Hc << 8) + base] + bias[3 * Hc + ch];
  float cp = cbuf[i];
  float si = 1.f / (1.f + expf(-iv));
  float sf = 1.f / (1.f + expf(-fv));
  float so = 1.f / (1.f + expf(-ov));
  float cn = sf * cp + si * tanhf(gv);
  float hn = so * tanhf(cn);
  cbuf[i] = cn;
  hbuf[i] = hn;
  if (hs) hs[i] = hn;
}

// ============================================================================
extern "C" void kernel_launch(void* const* d_in, const int* in_sizes, int n_in,
                              void* d_out, int out_size, void* d_ws, size_t ws_size,
                              hipStream_t stream)
{
  const float* h    = (const float*)d_in[0];
  const int*   objs = (const int*)  d_in[1];
  const float* c1w  = (const float*)d_in[3];
  const float* c2w  = (const float*)d_in[4];
  const float* c3w  = (const float*)d_in[5];
  const float* c4w  = (const float*)d_in[6];
  const float* c5w  = (const float*)d_in[7];
  const float* e1   = (const float*)d_in[8];
  const float* e2   = (const float*)d_in[9];
  const float* e3   = (const float*)d_in[10];
  const float* e4   = (const float*)d_in[11];
  const float* e5   = (const float*)d_in[12];
  const float* lw0  = (const float*)d_in[13];
  const float* lb0  = (const float*)d_in[14];
  const float* lw1  = (const float*)d_in[15];
  const float* lb1  = (const float*)d_in[16];
  const float* lw2  = (const float*)d_in[17];
  const float* lb2  = (const float*)d_in[18];

  // Workspace layout (aliased; ~105 MB total):
  //   region A (67.1 MB): x1, later x3, later x5
  //   region B (33.6 MB): x2, later x4
  //   smalls: stats, partials, lstm gate buf, h/c bufs, hs0, hs1
  char* ws = (char*)d_ws;
  float* x1 = (float*)ws;
  float* x3 = x1;
  float* x5 = x1;
  float* x2 = (float*)(ws + 67108864);
  float* x4 = x2;
  char* sm = ws + 67108864 + 33554432;
  float* stats = (float*)sm;  sm += 4096;
  float* part  = (float*)sm;  sm += 131072;
  float* ccb   = (float*)sm;  sm += (size_t)4 * 512 * 256 * 4;
  float* hb    = (float*)sm;  sm += (size_t)4 * 128 * 256 * 4;
  float* cb    = (float*)sm;  sm += (size_t)4 * 128 * 256 * 4;
  float* hs0   = (float*)sm;  sm += (size_t)2 * 4 * 128 * 256 * 4;
  float* hs1   = (float*)sm;  sm += (size_t)2 * 4 * 64 * 256 * 4;

  // ---- stage 1: conv1 (1x1, pad1) + cbn + lrelu ----
  hipMemsetAsync(x1, 0, (size_t)8 * 32 * 256 * 256 * 4, stream);
  conv1_kernel<<<dim3(64, 8), 256, 0, stream>>>(h, c1w, x1);
  meanvar_part_kernel<<<dim3(32, 32), 256, 0, stream>>>(x1, part, 32, 16, 8 << 16, 32);
  meanvar_fin_kernel<<<1, 64, 0, stream>>>(part, stats, 32, 32, 1.f / (float)(8 << 16));
  cbn_kernel<true><<<dim3(256, 32, 8), 256, 0, stream>>>(x1, stats, e1, objs, 32, 16);

  // ---- stage 2 ----
  conv4x4_kernel<32, 64, 256, 128, 16, 8, 1><<<dim3(64, 4, 8), 256, 0, stream>>>(x1, c2w, x2);
  meanvar_part_kernel<<<dim3(64, 16), 256, 0, stream>>>(x2, part, 64, 14, 8 << 14, 16);
  meanvar_fin_kernel<<<1, 64, 0, stream>>>(part, stats, 64, 16, 1.f / (float)(8 << 14));
  cbn_kernel<true><<<dim3(64, 64, 8), 256, 0, stream>>>(x2, stats, e2, objs, 64, 14);

  // ---- stage 3 ----
  conv4x4_kernel<64, 128, 128, 64, 16, 8, 1><<<dim3(16, 8, 8), 256, 0, stream>>>(x2, c3w, x3);
  meanvar_part_kernel<<<dim3(128, 8), 256, 0, stream>>>(x3, part, 128, 12, 8 << 12, 8);
  meanvar_fin_kernel<<<2, 64, 0, stream>>>(part, stats, 128, 8, 1.f / (float)(8 << 12));
  cbn_kernel<true><<<dim3(16, 128, 8), 256, 0, stream>>>(x3, stats, e3, objs, 128, 12);

  // ---- stage 4 (no lrelu) ----
  conv4x4_kernel<128, 256, 64, 32, 16, 8, 1><<<dim3(4, 16, 8), 256, 0, stream>>>(x3, c4w, x4);
  meanvar_part_kernel<<<dim3(256, 4), 256, 0, stream>>>(x4, part, 256, 10, 8 << 10, 4);
  meanvar_fin_kernel<<<4, 64, 0, stream>>>(part, stats, 256, 4, 1.f / (float)(8 << 10));
  cbn_kernel<false><<<dim3(4, 256, 8), 256, 0, stream>>>(x4, stats, e4, objs, 256, 10);

  // ---- stage 5 (no lrelu); CSPLIT=2 with atomics, pre-zero x5 ----
  hipMemsetAsync(x5, 0, (size_t)8 * 512 * 16 * 16 * 4, stream);
  conv4x4_kernel<256, 512, 32, 16, 16, 8, 2><<<dim3(1, 32, 16), 256, 0, stream>>>(x4, c5w, x5);
  meanvar_part_kernel<<<dim3(512, 4), 256, 0, stream>>>(x5, part, 512, 8, 8 << 8, 4);
  meanvar_fin_kernel<<<8, 64, 0, stream>>>(part, stats, 512, 4, 1.f / (float)(8 << 8));
  cbn_kernel<false><<<dim3(1, 512, 8), 256, 0, stream>>>(x5, stats, e5, objs, 512, 8);

  // ---- ConvLSTM 0: 512 -> 128 ----
  hipMemsetAsync(hb, 0, (size_t)4 * 128 * 256 * 4, stream);
  hipMemsetAsync(cb, 0, (size_t)4 * 128 * 256 * 4, stream);
  for (int t = 0; t < 2; ++t) {
    hipMemsetAsync(ccb, 0, (size_t)4 * 512 * 256 * 4, stream);
    // seq[t][b] = x5[b*2 + t] -> base x5 + t*512*256, batch stride 2*512*256
    conv5x5_kernel<512, 128, 16, 8, 8><<<dim3(32, 4, 8), 256, 0, stream>>>(
        x5 + (size_t)t * 512 * 256, 2 * 512 * 256, hb, lw0, ccb);
    lstm_point_kernel<<<dim3(4 * 128), 256, 0, stream>>>(
        ccb, lb0, cb, hb, hs0 + (size_t)t * 4 * 128 * 256, 7);
  }

  // ---- ConvLSTM 1: 128 -> 64 ----
  hipMemsetAsync(hb, 0, (size_t)4 * 64 * 256 * 4, stream);
  hipMemsetAsync(cb, 0, (size_t)4 * 64 * 256 * 4, stream);
  for (int t = 0; t < 2; ++t) {
    hipMemsetAsync(ccb, 0, (size_t)4 * 256 * 256 * 4, stream);
    conv5x5_kernel<128, 64, 16, 8, 8><<<dim3(16, 4, 8), 256, 0, stream>>>(
        hs0 + (size_t)t * 4 * 128 * 256, 128 * 256, hb, lw1, ccb);
    lstm_point_kernel<<<dim3(4 * 64), 256, 0, stream>>>(
        ccb, lb1, cb, hb, hs1 + (size_t)t * 4 * 64 * 256, 6);
  }

  // ---- ConvLSTM 2: 64 -> 64, final h -> d_out ----
  hipMemsetAsync(hb, 0, (size_t)4 * 64 * 256 * 4, stream);
  hipMemsetAsync(cb, 0, (size_t)4 * 64 * 256 * 4, stream);
  for (int t = 0; t < 2; ++t) {
    hipMemsetAsync(ccb, 0, (size_t)4 * 256 * 256 * 4, stream);
    conv5x5_kernel<64, 64, 16, 8, 8><<<dim3(16, 4, 8), 256, 0, stream>>>(
        hs1 + (size_t)t * 4 * 64 * 256, 64 * 256, hb, lw2, ccb);
    lstm_point_kernel<<<dim3(4 * 64), 256, 0, stream>>>(
        ccb, lb2, cb, hb, (t == 1) ? (float*)d_out : nullptr, 6);
  }
}

// Round 2
// 2393.742 us; speedup vs baseline: 1.1498x; 1.1498x over previous
//
#include <hip/hip_runtime.h>
#include <math.h>

#define LEAK 0.2f

typedef __attribute__((ext_vector_type(8))) short bf16x8;
typedef __attribute__((ext_vector_type(4))) float f32x4;

__device__ __forceinline__ unsigned short f2bf(float f) {
  unsigned u = __float_as_uint(f);
  u += 0x7FFFu + ((u >> 16) & 1u);
  return (unsigned short)(u >> 16);
}

// ---------------- conv1: 1x1 conv 512->32, pad=1 (border stays 0 from memset) ----
__global__ __launch_bounds__(256) void conv1_kernel(
    const float* __restrict__ h, const float* __restrict__ w, float* __restrict__ out)
{
  __shared__ float wt[256 * 32];
  const int n  = blockIdx.y;
  const int r0 = blockIdx.x * 4;
  const int ix = threadIdx.x;
  const bool lanev = (ix < 254);
  const bool rv2 = (r0 + 2) < 254, rv3 = (r0 + 3) < 254;

  float acc[4][32];
#pragma unroll
  for (int r = 0; r < 4; ++r)
#pragma unroll
    for (int o = 0; o < 32; ++o) acc[r][o] = 0.f;

  const float* hp = h + (size_t)n * 512 * 64516 + (size_t)r0 * 254 + ix;

  for (int half = 0; half < 2; ++half) {
    const int cbase = half * 256;
    for (int i = threadIdx.x; i < 256 * 32; i += 256) {
      int c = i >> 5, o = i & 31;
      wt[i] = w[(size_t)o * 512 + cbase + c];
    }
    __syncthreads();
    if (lanev) {
#pragma unroll 4
      for (int c = 0; c < 256; ++c) {
        const float* pc = hp + (size_t)(cbase + c) * 64516;
        float vr[4];
        vr[0] = pc[0];
        vr[1] = pc[254];
        vr[2] = rv2 ? pc[2 * 254] : 0.f;
        vr[3] = rv3 ? pc[3 * 254] : 0.f;
        const float4* wp = (const float4*)&wt[c * 32];
#pragma unroll
        for (int q = 0; q < 8; ++q) {
          float4 w4 = wp[q];
#pragma unroll
          for (int r = 0; r < 4; ++r) {
            acc[r][4 * q + 0] = fmaf(vr[r], w4.x, acc[r][4 * q + 0]);
            acc[r][4 * q + 1] = fmaf(vr[r], w4.y, acc[r][4 * q + 1]);
            acc[r][4 * q + 2] = fmaf(vr[r], w4.z, acc[r][4 * q + 2]);
            acc[r][4 * q + 3] = fmaf(vr[r], w4.w, acc[r][4 * q + 3]);
          }
        }
      }
    }
    __syncthreads();
  }

  if (lanev) {
    float* op = out + (size_t)n * 32 * 65536 + (size_t)(r0 + 1) * 256 + (ix + 1);
#pragma unroll
    for (int o = 0; o < 32; ++o) {
      float* oc = op + (size_t)o * 65536;
      oc[0]   = acc[0][o];
      oc[256] = acc[1][o];
      if (rv2) oc[512] = acc[2][o];
      if (rv3) oc[768] = acc[3][o];
    }
  }
}

// ---------------- generic 4x4 stride-2 pad-1 conv ---------------------------
template <int C, int O, int HIN, int HOUT, int OCH, int CCH, int CSPLIT>
__global__ __launch_bounds__(256) void conv4x4_kernel(
    const float* __restrict__ in, const float* __restrict__ w, float* __restrict__ out)
{
  constexpr int TW = HOUT / 16;
  __shared__ float tile_in[CCH][34 * 34];
  __shared__ float swt[CCH][16][OCH];

  const int tile = blockIdx.x, ty = tile / TW, tx = tile % TW;
  const int o0 = blockIdx.y * OCH;
  const int n = blockIdx.z / CSPLIT, cs = blockIdx.z % CSPLIT;
  const int px = threadIdx.x & 15, py = threadIdx.x >> 4;
  const int iy0 = ty * 32 - 1, ix0 = tx * 32 - 1;

  float acc[OCH];
#pragma unroll
  for (int i = 0; i < OCH; ++i) acc[i] = 0.f;

  constexpr int CPER = C / CSPLIT;
  const int cbeg = cs * CPER;

  for (int c0 = cbeg; c0 < cbeg + CPER; c0 += CCH) {
    for (int idx = threadIdx.x; idx < CCH * 34 * 34; idx += 256) {
      int cc = idx / (34 * 34);
      int r = idx - cc * (34 * 34);
      int yy = r / 34, xx = r - yy * 34;
      int iy = iy0 + yy, ix = ix0 + xx;
      float v = 0.f;
      if ((unsigned)iy < (unsigned)HIN && (unsigned)ix < (unsigned)HIN)
        v = in[(((size_t)n * C + (c0 + cc)) * HIN + iy) * HIN + ix];
      tile_in[cc][r] = v;
    }
    for (int idx = threadIdx.x; idx < CCH * 16 * OCH; idx += 256) {
      int cc = idx / (16 * OCH);
      int r = idx - cc * (16 * OCH);
      int k = r / OCH, oo = r - k * OCH;
      swt[cc][k][oo] = w[(((size_t)(o0 + oo) * C + (c0 + cc)) * 16) + k];
    }
    __syncthreads();

    const int ibase = (py * 2) * 34 + px * 2;
    for (int cc = 0; cc < CCH; ++cc) {
      const float* tin = &tile_in[cc][ibase];
#pragma unroll
      for (int ky = 0; ky < 4; ++ky)
#pragma unroll
        for (int kx = 0; kx < 4; ++kx) {
          float v = tin[ky * 34 + kx];
          const float4* wp = (const float4*)&swt[cc][ky * 4 + kx][0];
#pragma unroll
          for (int q = 0; q < OCH / 4; ++q) {
            float4 w4 = wp[q];
            acc[4 * q + 0] = fmaf(v, w4.x, acc[4 * q + 0]);
            acc[4 * q + 1] = fmaf(v, w4.y, acc[4 * q + 1]);
            acc[4 * q + 2] = fmaf(v, w4.z, acc[4 * q + 2]);
            acc[4 * q + 3] = fmaf(v, w4.w, acc[4 * q + 3]);
          }
        }
    }
    __syncthreads();
  }

  const int oy = ty * 16 + py, ox = tx * 16 + px;
  float* op = out + (((size_t)n * O + o0) * HOUT + oy) * HOUT + ox;
#pragma unroll
  for (int oo = 0; oo < OCH; ++oo) {
    if (CSPLIT > 1) atomicAdd(op + (size_t)oo * HOUT * HOUT, acc[oo]);
    else            op[(size_t)oo * HOUT * HOUT] = acc[oo];
  }
}

// ---------------- weight prep: [O][C][25] f32 -> [tap][O][C] bf16 ----------
__global__ __launch_bounds__(256) void wprep_kernel(
    const float* __restrict__ w, unsigned short* __restrict__ dst, int O, int C)
{
  int i = blockIdx.x * 256 + threadIdx.x;
  int tot = O * C * 25;
  if (i < tot) {
    int o = i / (C * 25);
    int r = i - o * C * 25;
    int c = r / 25, tap = r - c * 25;
    dst[((size_t)tap * O + o) * C + c] = f2bf(w[i]);
  }
}

// ---------------- MFMA 5x5 s1 p2 conv on 16x16 images (kn2row) --------------
// grid (O/64, B=4, KSPLIT); block 256 = 4 waves (wm=wid>>1 over M, wn=wid&1 over N).
// Per block: 64 out-ch x 256 pixels, K-chunk = NCHUNK*32 channels.
// Partials: pp[((ks*4 + b)*O + o)*256 + pix], summed later in lstm_point.
template <int O, int CX, int HH, int NCHUNK>
__global__ __launch_bounds__(256) void mfma_conv5_kernel(
    const float* __restrict__ xin, int xbstride, const float* __restrict__ hin,
    const unsigned short* __restrict__ wbf, float* __restrict__ pp)
{
  constexpr int C = CX + HH;
  __shared__ __align__(16) unsigned short inT[400 * 40];  // [padpix 20x20][40 slots], 32KB

  const int o0 = blockIdx.x * 64;
  const int b = blockIdx.y, ks = blockIdx.z;
  const int tid = threadIdx.x;
  const int lane = tid & 63, wid = tid >> 6;
  const int wm = wid >> 1, wn = wid & 1;
  const int ln15 = lane & 15, kg = lane >> 4;

  f32x4 acc[2][8];
#pragma unroll
  for (int m = 0; m < 2; ++m)
#pragma unroll
    for (int nt = 0; nt < 8; ++nt) acc[m][nt] = (f32x4){0.f, 0.f, 0.f, 0.f};

  for (int kc = 0; kc < NCHUNK; ++kc) {
    const int cbase = (ks * NCHUNK + kc) * 32;
    __syncthreads();
    // stage 32 channels, padded to 20x20, pixel-major bf16
    for (int idx = tid; idx < 32 * 400; idx += 256) {
      int c = idx / 400, pix = idx - c * 400;
      int pr = pix / 20, pc = pix - pr * 20;
      int ir = pr - 2, ic = pc - 2;
      float v = 0.f;
      int cg = cbase + c;
      if ((unsigned)ir < 16u && (unsigned)ic < 16u) {
        v = (cg < CX) ? xin[(size_t)b * xbstride + ((size_t)cg << 8) + (ir << 4) + ic]
                      : hin[(((size_t)b * HH + (cg - CX)) << 8) + (ir << 4) + ic];
      }
      inT[pix * 40 + c] = f2bf(v);
    }
    __syncthreads();

    for (int tap = 0; tap < 25; ++tap) {
      const int tty = tap / 5, ttx = tap - 5 * tty;
      const unsigned short* ap =
          wbf + ((size_t)tap * O + o0 + wm * 32 + ln15) * C + cbase + kg * 8;
      bf16x8 a0 = *(const bf16x8*)ap;
      bf16x8 a1 = *(const bf16x8*)(ap + (size_t)16 * C);
      const unsigned short* bp = &inT[((wn * 8 + tty) * 20 + ln15 + ttx) * 40 + kg * 8];
#pragma unroll
      for (int nt = 0; nt < 8; ++nt) {
        bf16x8 bf = *(const bf16x8*)(bp + nt * 20 * 40);
        acc[0][nt] = __builtin_amdgcn_mfma_f32_16x16x32_bf16(a0, bf, acc[0][nt], 0, 0, 0);
        acc[1][nt] = __builtin_amdgcn_mfma_f32_16x16x32_bf16(a1, bf, acc[1][nt], 0, 0, 0);
      }
    }
  }

  // write partials: C/D layout col=lane&15, row=(lane>>4)*4+r
  float* base = pp + ((size_t)(ks * 4 + b)) * O * 256;
#pragma unroll
  for (int mf = 0; mf < 2; ++mf) {
    const int o = o0 + wm * 32 + mf * 16 + kg * 4;
#pragma unroll
    for (int nt = 0; nt < 8; ++nt) {
      const int pix = wn * 128 + nt * 16 + ln15;
      float* dst = base + (size_t)o * 256 + pix;
      f32x4 v = acc[mf][nt];
      dst[0]   = v[0];
      dst[256] = v[1];
      dst[512] = v[2];
      dst[768] = v[3];
    }
  }
}

// ---------------- mean/var partials --------------------------------------
__global__ __launch_bounds__(256) void meanvar_part_kernel(
    const float* __restrict__ x, float* __restrict__ part,
    int C, int lhw, int ntot, int S)
{
  const int c = blockIdx.x, s = blockIdx.y;
  const int len = ntot / S;
  const int hwm = (1 << lhw) - 1;
  float sum = 0.f, sq = 0.f;
  for (int j = s * len + threadIdx.x; j < (s + 1) * len; j += 256) {
    int n = j >> lhw, p = j & hwm;
    float v = x[(((size_t)n * C + c) << lhw) + p];
    sum += v; sq += v * v;
  }
  for (int off = 32; off; off >>= 1) {
    sum += __shfl_down(sum, off);
    sq  += __shfl_down(sq, off);
  }
  __shared__ float red[2][4];
  const int wid = threadIdx.x >> 6;
  if ((threadIdx.x & 63) == 0) { red[0][wid] = sum; red[1][wid] = sq; }
  __syncthreads();
  if (threadIdx.x == 0) {
    sum = red[0][0] + red[0][1] + red[0][2] + red[0][3];
    sq  = red[1][0] + red[1][1] + red[1][2] + red[1][3];
    part[((size_t)c * S + s) * 2]     = sum;
    part[((size_t)c * S + s) * 2 + 1] = sq;
  }
}

// ---------------- cbn apply with inline finalize (+ optional lrelu) --------
template <bool LRELU>
__global__ __launch_bounds__(256) void cbn_kernel(
    float* __restrict__ x, const float* __restrict__ part, int S, float invN,
    const float* __restrict__ embed, const int* __restrict__ objs, int C, int lhw)
{
  const int c = blockIdx.y, n = blockIdx.z;
  const int p = blockIdx.x * 256 + threadIdx.x;
  float sum = 0.f, sq = 0.f;
  for (int s = 0; s < S; ++s) {
    sum += part[((size_t)c * S + s) * 2];
    sq  += part[((size_t)c * S + s) * 2 + 1];
  }
  const float mean = sum * invN;
  const float rstd = rsqrtf(sq * invN - mean * mean + 1e-5f);
  const int y = objs[n];
  const float gamma = embed[(size_t)y * 2 * C + c];
  const float beta  = embed[(size_t)y * 2 * C + C + c];
  const size_t i = (((size_t)n * C + c) << lhw) + p;
  float v = (x[i] - mean) * rstd * gamma + beta;
  if (LRELU) v = v >= 0.f ? v : LEAK * v;
  x[i] = v;
}

// ---------------- LSTM pointwise: sum K-partials + gates -> (c, h) ----------
__global__ __launch_bounds__(256) void lstm_point_kernel(
    const float* __restrict__ pp, int KS, const float* __restrict__ bias,
    float* __restrict__ cbuf, float* __restrict__ hbuf, float* __restrict__ hs, int lH)
{
  const int Hc = 1 << lH;
  const int i = blockIdx.x * 256 + threadIdx.x;
  const int p = i & 255;
  const int ch = (i >> 8) & (Hc - 1);
  const int b = i >> (8 + lH);
  const size_t bstr = ((size_t)Hc * 4) << 8;
  const size_t off = ((size_t)ch << 8) + p;
  float g0 = 0.f, g1 = 0.f, g2 = 0.f, g3 = 0.f;
  for (int ks = 0; ks < KS; ++ks) {
    const float* q = pp + (size_t)(ks * 4 + b) * bstr + off;
    g0 += q[0];
    g1 += q[(size_t)Hc << 8];
    g2 += q[(size_t)(2 * Hc) << 8];
    g3 += q[(size_t)(3 * Hc) << 8];
  }
  g0 += bias[ch];
  g1 += bias[Hc + ch];
  g2 += bias[2 * Hc + ch];
  g3 += bias[3 * Hc + ch];
  float cp = cbuf[i];
  float si = 1.f / (1.f + expf(-g0));
  float sf = 1.f / (1.f + expf(-g1));
  float so = 1.f / (1.f + expf(-g2));
  float cn = sf * cp + si * tanhf(g3);
  float hn = so * tanhf(cn);
  cbuf[i] = cn;
  hbuf[i] = hn;
  if (hs) hs[i] = hn;
}

// ============================================================================
extern "C" void kernel_launch(void* const* d_in, const int* in_sizes, int n_in,
                              void* d_out, int out_size, void* d_ws, size_t ws_size,
                              hipStream_t stream)
{
  const float* h    = (const float*)d_in[0];
  const int*   objs = (const int*)  d_in[1];
  const float* c1w  = (const float*)d_in[3];
  const float* c2w  = (const float*)d_in[4];
  const float* c3w  = (const float*)d_in[5];
  const float* c4w  = (const float*)d_in[6];
  const float* c5w  = (const float*)d_in[7];
  const float* e1   = (const float*)d_in[8];
  const float* e2   = (const float*)d_in[9];
  const float* e3   = (const float*)d_in[10];
  const float* e4   = (const float*)d_in[11];
  const float* e5   = (const float*)d_in[12];
  const float* lw0  = (const float*)d_in[13];
  const float* lb0  = (const float*)d_in[14];
  const float* lw1  = (const float*)d_in[15];
  const float* lb1  = (const float*)d_in[16];
  const float* lw2  = (const float*)d_in[17];
  const float* lb2  = (const float*)d_in[18];

  char* ws = (char*)d_ws;
  float* x1 = (float*)ws;                       // 67.1 MB (also x3, x5)
  float* x3 = x1;
  float* x5 = x1;
  float* x2 = (float*)(ws + 67108864);          // 33.6 MB (also x4)
  float* x4 = x2;
  char* sm = ws + 67108864 + 33554432;
  float* pp = (float*)sm;           sm += 20971520;        // K-split partials (max lstm0: 10*4*512*256*4)
  unsigned short* wbf0 = (unsigned short*)sm; sm += 16384000;  // 25*512*640*2
  unsigned short* wbf1 = (unsigned short*)sm; sm += 2457600;   // 25*256*192*2
  unsigned short* wbf2 = (unsigned short*)sm; sm += 1638400;   // 25*256*128*2
  float* part  = (float*)sm;  sm += 131072;
  float* hb    = (float*)sm;  sm += (size_t)4 * 128 * 256 * 4;
  float* cb    = (float*)sm;  sm += (size_t)4 * 128 * 256 * 4;
  float* hs0   = (float*)sm;  sm += (size_t)2 * 4 * 128 * 256 * 4;
  float* hs1   = (float*)sm;  sm += (size_t)2 * 4 * 64 * 256 * 4;

  // ---- weight prep for LSTM convs (bf16, [tap][o][c]) ----
  wprep_kernel<<<(512 * 640 * 25 + 255) / 256, 256, 0, stream>>>(lw0, wbf0, 512, 640);
  wprep_kernel<<<(256 * 192 * 25 + 255) / 256, 256, 0, stream>>>(lw1, wbf1, 256, 192);
  wprep_kernel<<<(256 * 128 * 25 + 255) / 256, 256, 0, stream>>>(lw2, wbf2, 256, 128);

  // ---- stage 1: conv1 (1x1, pad1) + cbn + lrelu ----
  hipMemsetAsync(x1, 0, (size_t)8 * 32 * 256 * 256 * 4, stream);
  conv1_kernel<<<dim3(64, 8), 256, 0, stream>>>(h, c1w, x1);
  meanvar_part_kernel<<<dim3(32, 32), 256, 0, stream>>>(x1, part, 32, 16, 8 << 16, 32);
  cbn_kernel<true><<<dim3(256, 32, 8), 256, 0, stream>>>(x1, part, 32, 1.f / (float)(8 << 16), e1, objs, 32, 16);

  // ---- stage 2 ----
  conv4x4_kernel<32, 64, 256, 128, 32, 4, 1><<<dim3(64, 2, 8), 256, 0, stream>>>(x1, c2w, x2);
  meanvar_part_kernel<<<dim3(64, 16), 256, 0, stream>>>(x2, part, 64, 14, 8 << 14, 16);
  cbn_kernel<true><<<dim3(64, 64, 8), 256, 0, stream>>>(x2, part, 16, 1.f / (float)(8 << 14), e2, objs, 64, 14);

  // ---- stage 3 ----
  conv4x4_kernel<64, 128, 128, 64, 32, 4, 1><<<dim3(16, 4, 8), 256, 0, stream>>>(x2, c3w, x3);
  meanvar_part_kernel<<<dim3(128, 8), 256, 0, stream>>>(x3, part, 128, 12, 8 << 12, 8);
  cbn_kernel<true><<<dim3(16, 128, 8), 256, 0, stream>>>(x3, part, 8, 1.f / (float)(8 << 12), e3, objs, 128, 12);

  // ---- stage 4 (no lrelu) ----
  conv4x4_kernel<128, 256, 64, 32, 32, 4, 1><<<dim3(4, 8, 8), 256, 0, stream>>>(x3, c4w, x4);
  meanvar_part_kernel<<<dim3(256, 4), 256, 0, stream>>>(x4, part, 256, 10, 8 << 10, 4);
  cbn_kernel<false><<<dim3(4, 256, 8), 256, 0, stream>>>(x4, part, 4, 1.f / (float)(8 << 10), e4, objs, 256, 10);

  // ---- stage 5 (no lrelu) ----
  conv4x4_kernel<256, 512, 32, 16, 16, 8, 1><<<dim3(1, 32, 8), 256, 0, stream>>>(x4, c5w, x5);
  meanvar_part_kernel<<<dim3(512, 4), 256, 0, stream>>>(x5, part, 512, 8, 8 << 8, 4);
  cbn_kernel<false><<<dim3(1, 512, 8), 256, 0, stream>>>(x5, part, 4, 1.f / (float)(8 << 8), e5, objs, 512, 8);

  // ---- ConvLSTM 0: 512 -> 128 (C=640, KSPLIT=10, 2 chunks/block) ----
  hipMemsetAsync(hb, 0, (size_t)4 * 128 * 256 * 4, stream);
  hipMemsetAsync(cb, 0, (size_t)4 * 128 * 256 * 4, stream);
  for (int t = 0; t < 2; ++t) {
    mfma_conv5_kernel<512, 512, 128, 2><<<dim3(8, 4, 10), 256, 0, stream>>>(
        x5 + (size_t)t * 512 * 256, 2 * 512 * 256, hb, wbf0, pp);
    lstm_point_kernel<<<dim3(4 * 128), 256, 0, stream>>>(
        pp, 10, lb0, cb, hb, hs0 + (size_t)t * 4 * 128 * 256, 7);
  }

  // ---- ConvLSTM 1: 128 -> 64 (C=192, KSPLIT=6) ----
  hipMemsetAsync(hb, 0, (size_t)4 * 64 * 256 * 4, stream);
  hipMemsetAsync(cb, 0, (size_t)4 * 64 * 256 * 4, stream);
  for (int t = 0; t < 2; ++t) {
    mfma_conv5_kernel<256, 128, 64, 1><<<dim3(4, 4, 6), 256, 0, stream>>>(
        hs0 + (size_t)t * 4 * 128 * 256, 128 * 256, hb, wbf1, pp);
    lstm_point_kernel<<<dim3(4 * 64), 256, 0, stream>>>(
        pp, 6, lb1, cb, hb, hs1 + (size_t)t * 4 * 64 * 256, 6);
  }

  // ---- ConvLSTM 2: 64 -> 64 (C=128, KSPLIT=4), final h -> d_out ----
  hipMemsetAsync(hb, 0, (size_t)4 * 64 * 256 * 4, stream);
  hipMemsetAsync(cb, 0, (size_t)4 * 64 * 256 * 4, stream);
  for (int t = 0; t < 2; ++t) {
    mfma_conv5_kernel<256, 64, 64, 1><<<dim3(4, 4, 4), 256, 0, stream>>>(
        hs1 + (size_t)t * 4 * 64 * 256, 64 * 256, hb, wbf2, pp);
    lstm_point_kernel<<<dim3(4 * 64), 256, 0, stream>>>(
        pp, 4, lb2, cb, hb, (t == 1) ? (float*)d_out : nullptr, 6);
  }
}

// Round 3
// 1568.374 us; speedup vs baseline: 1.7549x; 1.5263x over previous
//
#include <hip/hip_runtime.h>
#include <math.h>

#define LEAK 0.2f

typedef __attribute__((ext_vector_type(8))) short bf16x8;
typedef __attribute__((ext_vector_type(4))) float f32x4;

__device__ __forceinline__ unsigned short f2bf(float f) {
  unsigned u = __float_as_uint(f);
  u += 0x7FFFu + ((u >> 16) & 1u);
  return (unsigned short)(u >> 16);
}

// ---------------- conv1: 1x1 conv 512->32, pad=1 (border stays 0 from memset) ----
__global__ __launch_bounds__(256) void conv1_kernel(
    const float* __restrict__ h, const float* __restrict__ w, float* __restrict__ out)
{
  __shared__ float wt[256 * 32];
  const int n  = blockIdx.y;
  const int r0 = blockIdx.x * 4;
  const int ix = threadIdx.x;
  const bool lanev = (ix < 254);
  const bool rv2 = (r0 + 2) < 254, rv3 = (r0 + 3) < 254;

  float acc[4][32];
#pragma unroll
  for (int r = 0; r < 4; ++r)
#pragma unroll
    for (int o = 0; o < 32; ++o) acc[r][o] = 0.f;

  const float* hp = h + (size_t)n * 512 * 64516 + (size_t)r0 * 254 + ix;

  for (int half = 0; half < 2; ++half) {
    const int cbase = half * 256;
    for (int i = threadIdx.x; i < 256 * 32; i += 256) {
      int c = i >> 5, o = i & 31;
      wt[i] = w[(size_t)o * 512 + cbase + c];
    }
    __syncthreads();
    if (lanev) {
#pragma unroll 4
      for (int c = 0; c < 256; ++c) {
        const float* pc = hp + (size_t)(cbase + c) * 64516;
        float vr[4];
        vr[0] = pc[0];
        vr[1] = pc[254];
        vr[2] = rv2 ? pc[2 * 254] : 0.f;
        vr[3] = rv3 ? pc[3 * 254] : 0.f;
        const float4* wp = (const float4*)&wt[c * 32];
#pragma unroll
        for (int q = 0; q < 8; ++q) {
          float4 w4 = wp[q];
#pragma unroll
          for (int r = 0; r < 4; ++r) {
            acc[r][4 * q + 0] = fmaf(vr[r], w4.x, acc[r][4 * q + 0]);
            acc[r][4 * q + 1] = fmaf(vr[r], w4.y, acc[r][4 * q + 1]);
            acc[r][4 * q + 2] = fmaf(vr[r], w4.z, acc[r][4 * q + 2]);
            acc[r][4 * q + 3] = fmaf(vr[r], w4.w, acc[r][4 * q + 3]);
          }
        }
      }
    }
    __syncthreads();
  }

  if (lanev) {
    float* op = out + (size_t)n * 32 * 65536 + (size_t)(r0 + 1) * 256 + (ix + 1);
#pragma unroll
    for (int o = 0; o < 32; ++o) {
      float* oc = op + (size_t)o * 65536;
      oc[0]   = acc[0][o];
      oc[256] = acc[1][o];
      if (rv2) oc[512] = acc[2][o];
      if (rv3) oc[768] = acc[3][o];
    }
  }
}

// ---------------- weight prep: [O][C][TAPS] f32 -> [tap][O][C] bf16 ---------
__global__ __launch_bounds__(256) void wprep_kernel(
    const float* __restrict__ w, unsigned short* __restrict__ dst, int O, int C, int TAPS)
{
  int i = blockIdx.x * 256 + threadIdx.x;
  int tot = O * C * TAPS;
  if (i < tot) {
    int o = i / (C * TAPS);
    int r = i - o * C * TAPS;
    int c = r / TAPS, tap = r - c * TAPS;
    dst[((size_t)tap * O + o) * C + c] = f2bf(w[i]);
  }
}

// ---------------- unified MFMA 4x4 stride-2 pad-1 conv ----------------------
// Input HIN=2*HOUT square, output HOUT square. Block: 4 waves = WM(over O) x WN(over pix).
// Block covers 64 out-ch (WM=2) x ROWS*COLS output pixels. K-chunks of 32 in-ch.
// LDS: pad tile, column-parity-split layout so fixed-tap reads are stride-40 (2-way banks).
template <int C, int O, int HOUT, int ROWS, int COLS, int WM, int WN>
__global__ __launch_bounds__(256) void mfma_conv4_kernel(
    const float* __restrict__ in, const unsigned short* __restrict__ wbf,
    float* __restrict__ out)
{
  constexpr int HIN = 2 * HOUT;
  constexpr int RPAD = 2 * ROWS + 2;
  constexpr int CPAD = 2 * COLS + 2;
  constexpr int NPP = RPAD * CPAD;          // pad-tile pixel count (== LDS slots)
  constexpr int FNT = ROWS * COLS / 16;     // total N fragments
  constexpr int FN = FNT / WN;              // N fragments per wave
  constexpr int XB = HOUT / COLS;           // blocks per row-band
  constexpr int H2 = HOUT * HOUT;
  constexpr int KC = C / 32;

  __shared__ __align__(16) unsigned short inT[NPP * 40];

  const int o0 = blockIdx.x * (WM * 32);
  const int strip = blockIdx.y;
  const int n = blockIdx.z;
  const int y0 = (strip / XB) * ROWS;
  const int x0 = (strip % XB) * COLS;
  const int in_y0 = 2 * y0 - 1, in_x0 = 2 * x0 - 1;

  const int tid = threadIdx.x;
  const int lane = tid & 63, wid = tid >> 6;
  const int wm = wid / WN, wn = wid % WN;
  const int ln15 = lane & 15, kg = lane >> 4;

  f32x4 acc[2][FN];
#pragma unroll
  for (int m = 0; m < 2; ++m)
#pragma unroll
    for (int nt = 0; nt < FN; ++nt) acc[m][nt] = (f32x4){0.f, 0.f, 0.f, 0.f};

  // per-frag pixel decomposition (lane-uniform part)
  int py_nt[FN], pxb_nt[FN];
#pragma unroll
  for (int nt = 0; nt < FN; ++nt) {
    int g = wn * FN + nt;
    py_nt[nt] = (g * 16) / COLS;
    pxb_nt[nt] = (g * 16) % COLS;
  }

  for (int kc = 0; kc < KC; ++kc) {
    const int cbase = kc * 32;
    __syncthreads();
    // stage 32 channels of the pad tile, parity-split pixel-major bf16
    for (int e = tid; e < 32 * NPP; e += 256) {
      int c = e / NPP;
      int r = e - c * NPP;
      int ly = r / CPAD, lx = r - ly * CPAD;
      int gy = in_y0 + ly, gx = in_x0 + lx;
      float v = 0.f;
      if ((unsigned)gy < (unsigned)HIN && (unsigned)gx < (unsigned)HIN)
        v = in[(((size_t)n * C + cbase + c) * HIN + gy) * HIN + gx];
      int LP = (ly * 2 + (lx & 1)) * (COLS + 1) + (lx >> 1);
      inT[LP * 40 + c] = f2bf(v);
    }
    __syncthreads();

#pragma unroll
    for (int tap = 0; tap < 16; ++tap) {
      const int ky = tap >> 2, kx = tap & 3;
      const unsigned short* ap =
          wbf + ((size_t)tap * O + o0 + wm * 32 + ln15) * C + cbase + kg * 8;
      bf16x8 a0 = *(const bf16x8*)ap;
      bf16x8 a1 = *(const bf16x8*)(ap + (size_t)16 * C);
#pragma unroll
      for (int nt = 0; nt < FN; ++nt) {
        int LP = ((2 * py_nt[nt] + ky) * 2 + (kx & 1)) * (COLS + 1)
                 + pxb_nt[nt] + ln15 + (kx >> 1);
        bf16x8 bf = *(const bf16x8*)&inT[LP * 40 + kg * 8];
        acc[0][nt] = __builtin_amdgcn_mfma_f32_16x16x32_bf16(a0, bf, acc[0][nt], 0, 0, 0);
        acc[1][nt] = __builtin_amdgcn_mfma_f32_16x16x32_bf16(a1, bf, acc[1][nt], 0, 0, 0);
      }
    }
  }

  // write: D row = o offset (kg*4 + r), col = pixel (ln15)
  const int oW = o0 + wm * 32;
#pragma unroll
  for (int mf = 0; mf < 2; ++mf) {
    const int obase = oW + mf * 16 + kg * 4;
#pragma unroll
    for (int nt = 0; nt < FN; ++nt) {
      const int gp = (y0 + py_nt[nt]) * HOUT + x0 + pxb_nt[nt] + ln15;
      float* dst = out + ((size_t)n * O + obase) * H2 + gp;
      f32x4 v = acc[mf][nt];
      dst[0]      = v[0];
      dst[H2]     = v[1];
      dst[2 * H2] = v[2];
      dst[3 * H2] = v[3];
    }
  }
}

// ---------------- MFMA 5x5 s1 p2 conv on 16x16 images (ConvLSTM) ------------
template <int O, int CX, int HH, int NCHUNK>
__global__ __launch_bounds__(256) void mfma_conv5_kernel(
    const float* __restrict__ xin, int xbstride, const float* __restrict__ hin,
    const unsigned short* __restrict__ wbf, float* __restrict__ pp)
{
  constexpr int C = CX + HH;
  __shared__ __align__(16) unsigned short inT[400 * 40];

  const int o0 = blockIdx.x * 64;
  const int b = blockIdx.y, ks = blockIdx.z;
  const int tid = threadIdx.x;
  const int lane = tid & 63, wid = tid >> 6;
  const int wm = wid >> 1, wn = wid & 1;
  const int ln15 = lane & 15, kg = lane >> 4;

  f32x4 acc[2][8];
#pragma unroll
  for (int m = 0; m < 2; ++m)
#pragma unroll
    for (int nt = 0; nt < 8; ++nt) acc[m][nt] = (f32x4){0.f, 0.f, 0.f, 0.f};

  for (int kc = 0; kc < NCHUNK; ++kc) {
    const int cbase = (ks * NCHUNK + kc) * 32;
    __syncthreads();
    for (int idx = tid; idx < 32 * 400; idx += 256) {
      int c = idx / 400, pix = idx - c * 400;
      int pr = pix / 20, pc = pix - pr * 20;
      int ir = pr - 2, ic = pc - 2;
      float v = 0.f;
      int cg = cbase + c;
      if ((unsigned)ir < 16u && (unsigned)ic < 16u) {
        v = (cg < CX) ? xin[(size_t)b * xbstride + ((size_t)cg << 8) + (ir << 4) + ic]
                      : hin[(((size_t)b * HH + (cg - CX)) << 8) + (ir << 4) + ic];
      }
      inT[pix * 40 + c] = f2bf(v);
    }
    __syncthreads();

    for (int tap = 0; tap < 25; ++tap) {
      const int tty = tap / 5, ttx = tap - 5 * tty;
      const unsigned short* ap =
          wbf + ((size_t)tap * O + o0 + wm * 32 + ln15) * C + cbase + kg * 8;
      bf16x8 a0 = *(const bf16x8*)ap;
      bf16x8 a1 = *(const bf16x8*)(ap + (size_t)16 * C);
      const unsigned short* bp = &inT[((wn * 8 + tty) * 20 + ln15 + ttx) * 40 + kg * 8];
#pragma unroll
      for (int nt = 0; nt < 8; ++nt) {
        bf16x8 bf = *(const bf16x8*)(bp + nt * 20 * 40);
        acc[0][nt] = __builtin_amdgcn_mfma_f32_16x16x32_bf16(a0, bf, acc[0][nt], 0, 0, 0);
        acc[1][nt] = __builtin_amdgcn_mfma_f32_16x16x32_bf16(a1, bf, acc[1][nt], 0, 0, 0);
      }
    }
  }

  float* base = pp + ((size_t)(ks * 4 + b)) * O * 256;
#pragma unroll
  for (int mf = 0; mf < 2; ++mf) {
    const int o = o0 + wm * 32 + mf * 16 + kg * 4;
#pragma unroll
    for (int nt = 0; nt < 8; ++nt) {
      const int pix = wn * 128 + nt * 16 + ln15;
      float* dst = base + (size_t)o * 256 + pix;
      f32x4 v = acc[mf][nt];
      dst[0]   = v[0];
      dst[256] = v[1];
      dst[512] = v[2];
      dst[768] = v[3];
    }
  }
}

// ---------------- mean/var partials ----------------------------------------
__global__ __launch_bounds__(256) void meanvar_part_kernel(
    const float* __restrict__ x, float* __restrict__ part,
    int C, int lhw, int ntot, int S)
{
  const int c = blockIdx.x, s = blockIdx.y;
  const int len = ntot / S;
  const int hwm = (1 << lhw) - 1;
  float sum = 0.f, sq = 0.f;
  for (int j = s * len + threadIdx.x; j < (s + 1) * len; j += 256) {
    int n = j >> lhw, p = j & hwm;
    float v = x[(((size_t)n * C + c) << lhw) + p];
    sum += v; sq += v * v;
  }
  for (int off = 32; off; off >>= 1) {
    sum += __shfl_down(sum, off);
    sq  += __shfl_down(sq, off);
  }
  __shared__ float red[2][4];
  const int wid = threadIdx.x >> 6;
  if ((threadIdx.x & 63) == 0) { red[0][wid] = sum; red[1][wid] = sq; }
  __syncthreads();
  if (threadIdx.x == 0) {
    sum = red[0][0] + red[0][1] + red[0][2] + red[0][3];
    sq  = red[1][0] + red[1][1] + red[1][2] + red[1][3];
    part[((size_t)c * S + s) * 2]     = sum;
    part[((size_t)c * S + s) * 2 + 1] = sq;
  }
}

// ---------------- cbn apply with inline finalize (+ optional lrelu) ---------
template <bool LRELU>
__global__ __launch_bounds__(256) void cbn_kernel(
    float* __restrict__ x, const float* __restrict__ part, int S, float invN,
    const float* __restrict__ embed, const int* __restrict__ objs, int C, int lhw)
{
  const int c = blockIdx.y, n = blockIdx.z;
  const int p = blockIdx.x * 256 + threadIdx.x;
  float sum = 0.f, sq = 0.f;
  for (int s = 0; s < S; ++s) {
    sum += part[((size_t)c * S + s) * 2];
    sq  += part[((size_t)c * S + s) * 2 + 1];
  }
  const float mean = sum * invN;
  const float rstd = rsqrtf(sq * invN - mean * mean + 1e-5f);
  const int y = objs[n];
  const float gamma = embed[(size_t)y * 2 * C + c];
  const float beta  = embed[(size_t)y * 2 * C + C + c];
  const size_t i = (((size_t)n * C + c) << lhw) + p;
  float v = (x[i] - mean) * rstd * gamma + beta;
  if (LRELU) v = v >= 0.f ? v : LEAK * v;
  x[i] = v;
}

// ---------------- LSTM pointwise: sum K-partials + gates -> (c, h) ----------
__global__ __launch_bounds__(256) void lstm_point_kernel(
    const float* __restrict__ pp, int KS, const float* __restrict__ bias,
    float* __restrict__ cbuf, float* __restrict__ hbuf, float* __restrict__ hs, int lH)
{
  const int Hc = 1 << lH;
  const int i = blockIdx.x * 256 + threadIdx.x;
  const int p = i & 255;
  const int ch = (i >> 8) & (Hc - 1);
  const int b = i >> (8 + lH);
  const size_t bstr = ((size_t)Hc * 4) << 8;
  const size_t off = ((size_t)ch << 8) + p;
  float g0 = 0.f, g1 = 0.f, g2 = 0.f, g3 = 0.f;
  for (int ks = 0; ks < KS; ++ks) {
    const float* q = pp + (size_t)(ks * 4 + b) * bstr + off;
    g0 += q[0];
    g1 += q[(size_t)Hc << 8];
    g2 += q[(size_t)(2 * Hc) << 8];
    g3 += q[(size_t)(3 * Hc) << 8];
  }
  g0 += bias[ch];
  g1 += bias[Hc + ch];
  g2 += bias[2 * Hc + ch];
  g3 += bias[3 * Hc + ch];
  float cp = cbuf[i];
  float si = 1.f / (1.f + expf(-g0));
  float sf = 1.f / (1.f + expf(-g1));
  float so = 1.f / (1.f + expf(-g2));
  float cn = sf * cp + si * tanhf(g3);
  float hn = so * tanhf(cn);
  cbuf[i] = cn;
  hbuf[i] = hn;
  if (hs) hs[i] = hn;
}

// ============================================================================
extern "C" void kernel_launch(void* const* d_in, const int* in_sizes, int n_in,
                              void* d_out, int out_size, void* d_ws, size_t ws_size,
                              hipStream_t stream)
{
  const float* h    = (const float*)d_in[0];
  const int*   objs = (const int*)  d_in[1];
  const float* c1w  = (const float*)d_in[3];
  const float* c2w  = (const float*)d_in[4];
  const float* c3w  = (const float*)d_in[5];
  const float* c4w  = (const float*)d_in[6];
  const float* c5w  = (const float*)d_in[7];
  const float* e1   = (const float*)d_in[8];
  const float* e2   = (const float*)d_in[9];
  const float* e3   = (const float*)d_in[10];
  const float* e4   = (const float*)d_in[11];
  const float* e5   = (const float*)d_in[12];
  const float* lw0  = (const float*)d_in[13];
  const float* lb0  = (const float*)d_in[14];
  const float* lw1  = (const float*)d_in[15];
  const float* lb1  = (const float*)d_in[16];
  const float* lw2  = (const float*)d_in[17];
  const float* lb2  = (const float*)d_in[18];

  char* ws = (char*)d_ws;
  float* x1 = (float*)ws;                       // 67.1 MB (also x3, x5)
  float* x3 = x1;
  float* x5 = x1;
  float* x2 = (float*)(ws + 67108864);          // 33.6 MB (also x4)
  float* x4 = x2;
  char* sm = ws + 67108864 + 33554432;
  float* pp = (float*)sm;           sm += 20971520;            // LSTM K-split partials
  unsigned short* wbf0 = (unsigned short*)sm; sm += 16384000;  // 25*512*640*2
  unsigned short* wbf1 = (unsigned short*)sm; sm += 2457600;   // 25*256*192*2
  unsigned short* wbf2 = (unsigned short*)sm; sm += 1638400;   // 25*256*128*2
  unsigned short* wb2  = (unsigned short*)sm; sm += 2 * 16 * 64 * 32;     // conv2
  unsigned short* wb3  = (unsigned short*)sm; sm += 2 * 16 * 128 * 64;    // conv3
  unsigned short* wb4  = (unsigned short*)sm; sm += 2 * 16 * 256 * 128;   // conv4
  unsigned short* wb5  = (unsigned short*)sm; sm += 2 * 16 * 512 * 256;   // conv5
  float* part  = (float*)sm;  sm += 131072;
  float* hb    = (float*)sm;  sm += (size_t)4 * 128 * 256 * 4;
  float* cb    = (float*)sm;  sm += (size_t)4 * 128 * 256 * 4;
  float* hs0   = (float*)sm;  sm += (size_t)2 * 4 * 128 * 256 * 4;
  float* hs1   = (float*)sm;  sm += (size_t)2 * 4 * 64 * 256 * 4;

  // ---- weight prep (bf16, [tap][o][c]) ----
  wprep_kernel<<<(512 * 640 * 25 + 255) / 256, 256, 0, stream>>>(lw0, wbf0, 512, 640, 25);
  wprep_kernel<<<(256 * 192 * 25 + 255) / 256, 256, 0, stream>>>(lw1, wbf1, 256, 192, 25);
  wprep_kernel<<<(256 * 128 * 25 + 255) / 256, 256, 0, stream>>>(lw2, wbf2, 256, 128, 25);
  wprep_kernel<<<(64 * 32 * 16 + 255) / 256, 256, 0, stream>>>(c2w, wb2, 64, 32, 16);
  wprep_kernel<<<(128 * 64 * 16 + 255) / 256, 256, 0, stream>>>(c3w, wb3, 128, 64, 16);
  wprep_kernel<<<(256 * 128 * 16 + 255) / 256, 256, 0, stream>>>(c4w, wb4, 256, 128, 16);
  wprep_kernel<<<(512 * 256 * 16 + 255) / 256, 256, 0, stream>>>(c5w, wb5, 512, 256, 16);

  // ---- stage 1: conv1 (1x1, pad1) + cbn + lrelu ----
  hipMemsetAsync(x1, 0, (size_t)8 * 32 * 256 * 256 * 4, stream);
  conv1_kernel<<<dim3(64, 8), 256, 0, stream>>>(h, c1w, x1);
  meanvar_part_kernel<<<dim3(32, 32), 256, 0, stream>>>(x1, part, 32, 16, 8 << 16, 32);
  cbn_kernel<true><<<dim3(256, 32, 8), 256, 0, stream>>>(x1, part, 32, 1.f / (float)(8 << 16), e1, objs, 32, 16);

  // ---- stage 2: 32 -> 64, 256 -> 128 ----
  mfma_conv4_kernel<32, 64, 128, 1, 64, 2, 2><<<dim3(1, 256, 8), 256, 0, stream>>>(x1, wb2, x2);
  meanvar_part_kernel<<<dim3(64, 16), 256, 0, stream>>>(x2, part, 64, 14, 8 << 14, 16);
  cbn_kernel<true><<<dim3(64, 64, 8), 256, 0, stream>>>(x2, part, 16, 1.f / (float)(8 << 14), e2, objs, 64, 14);

  // ---- stage 3: 64 -> 128, 128 -> 64 ----
  mfma_conv4_kernel<64, 128, 64, 2, 64, 2, 2><<<dim3(2, 32, 8), 256, 0, stream>>>(x2, wb3, x3);
  meanvar_part_kernel<<<dim3(128, 8), 256, 0, stream>>>(x3, part, 128, 12, 8 << 12, 8);
  cbn_kernel<true><<<dim3(16, 128, 8), 256, 0, stream>>>(x3, part, 8, 1.f / (float)(8 << 12), e3, objs, 128, 12);

  // ---- stage 4: 128 -> 256, 64 -> 32 (no lrelu) ----
  mfma_conv4_kernel<128, 256, 32, 4, 32, 2, 2><<<dim3(4, 8, 8), 256, 0, stream>>>(x3, wb4, x4);
  meanvar_part_kernel<<<dim3(256, 4), 256, 0, stream>>>(x4, part, 256, 10, 8 << 10, 4);
  cbn_kernel<false><<<dim3(4, 256, 8), 256, 0, stream>>>(x4, part, 4, 1.f / (float)(8 << 10), e4, objs, 256, 10);

  // ---- stage 5: 256 -> 512, 32 -> 16 (no lrelu) ----
  mfma_conv4_kernel<256, 512, 16, 8, 16, 2, 2><<<dim3(8, 2, 8), 256, 0, stream>>>(x4, wb5, x5);
  meanvar_part_kernel<<<dim3(512, 4), 256, 0, stream>>>(x5, part, 512, 8, 8 << 8, 4);
  cbn_kernel<false><<<dim3(1, 512, 8), 256, 0, stream>>>(x5, part, 4, 1.f / (float)(8 << 8), e5, objs, 512, 8);

  // ---- ConvLSTM 0: 512 -> 128 (C=640, KSPLIT=10, 2 chunks/block) ----
  hipMemsetAsync(hb, 0, (size_t)4 * 128 * 256 * 4, stream);
  hipMemsetAsync(cb, 0, (size_t)4 * 128 * 256 * 4, stream);
  for (int t = 0; t < 2; ++t) {
    mfma_conv5_kernel<512, 512, 128, 2><<<dim3(8, 4, 10), 256, 0, stream>>>(
        x5 + (size_t)t * 512 * 256, 2 * 512 * 256, hb, wbf0, pp);
    lstm_point_kernel<<<dim3(4 * 128), 256, 0, stream>>>(
        pp, 10, lb0, cb, hb, hs0 + (size_t)t * 4 * 128 * 256, 7);
  }

  // ---- ConvLSTM 1: 128 -> 64 (C=192, KSPLIT=6) ----
  hipMemsetAsync(hb, 0, (size_t)4 * 64 * 256 * 4, stream);
  hipMemsetAsync(cb, 0, (size_t)4 * 64 * 256 * 4, stream);
  for (int t = 0; t < 2; ++t) {
    mfma_conv5_kernel<256, 128, 64, 1><<<dim3(4, 4, 6), 256, 0, stream>>>(
        hs0 + (size_t)t * 4 * 128 * 256, 128 * 256, hb, wbf1, pp);
    lstm_point_kernel<<<dim3(4 * 64), 256, 0, stream>>>(
        pp, 6, lb1, cb, hb, hs1 + (size_t)t * 4 * 64 * 256, 6);
  }

  // ---- ConvLSTM 2: 64 -> 64 (C=128, KSPLIT=4), final h -> d_out ----
  hipMemsetAsync(hb, 0, (size_t)4 * 64 * 256 * 4, stream);
  hipMemsetAsync(cb, 0, (size_t)4 * 64 * 256 * 4, stream);
  for (int t = 0; t < 2; ++t) {
    mfma_conv5_kernel<256, 64, 64, 1><<<dim3(4, 4, 4), 256, 0, stream>>>(
        hs1 + (size_t)t * 4 * 64 * 256, 64 * 256, hb, wbf2, pp);
    lstm_point_kernel<<<dim3(4 * 64), 256, 0, stream>>>(
        pp, 4, lb2, cb, hb, (t == 1) ? (float*)d_out : nullptr, 6);
  }
}